// Round 5
// baseline (180.997 us; speedup 1.0000x reference)
//
#include <hip/hip_runtime.h>
#include <math.h>

#define JT 64                // j per job (LDS staged)
#define ITILE 1024           // i per job (4 per thread, 256 threads)
#define T8 8                 // 1024-tiles per dimension
#define NJOB_AB 1024         // 8 i-tiles * 128 j-chunks
#define NJOB_TRI 576         // 36 tri-tiles * 16 chunks
#define NJOB (NJOB_AB + 2 * NJOB_TRI)  // 2176 jobs
#define GRID 2048            // persistent blocks (queue-drained)
#define L2E 1.4426950408889634f

typedef float v2f __attribute__((ext_vector_type(2)));

// exp2(-x) in ONE instruction: neg folded into VOP3 input modifier.
__device__ inline float fexp2n(float x) {
  float r;
  asm("v_exp_f32 %0, -%1" : "=v"(r) : "v"(x));
  return r;
}
__device__ inline float fsqrt(float x) {
  float r;
  asm("v_sqrt_f32 %0, %1" : "=v"(r) : "v"(x));
  return r;
}

__device__ inline double wred_d(double v) {
#pragma unroll
  for (int o = 32; o > 0; o >>= 1) v += __shfl_down(v, o, 64);
  return v;
}

__device__ inline double bred(double v, double* sm) {
  v = wred_d(v);
  __syncthreads();
  if ((threadIdx.x & 63) == 0) sm[threadIdx.x >> 6] = v;
  __syncthreads();
  return sm[0] + sm[1] + sm[2] + sm[3];
}

// wave 0: reduce 64 prep slots (stride 8) -> smean[c]=base, smean[8+c]=target
__device__ inline void slot_reduce(const double* slot, double* smean, int nc) {
  if (threadIdx.x < 64) {
    int l = threadIdx.x;
    const double* sl = slot + l * 8;
    for (int c = 0; c < nc; ++c) {
      double v = sl[c];
      double vb = (l < 32) ? v : 0.0;
      double vt = (l < 32) ? 0.0 : v;
      vb = wred_d(vb);
      vt = wred_d(vt);
      if (l == 0) {
        smean[c] = vb;
        smean[8 + c] = vt;
      }
    }
  }
}

__global__ __launch_bounds__(256) void prep_kernel(
    const float* __restrict__ base, const float* __restrict__ target,
    const float* __restrict__ log_sigmas, const float* __restrict__ log_scale,
    const float* __restrict__ w1, const float* __restrict__ b1,
    const float* __restrict__ w2, const float* __restrict__ b2,
    float2* __restrict__ pxy, float* __restrict__ pu,
    double* __restrict__ slot, unsigned* __restrict__ fctr,
    unsigned* __restrict__ qctr, int n) {
  __shared__ double sm[4];
  int gid = blockIdx.x * 256 + threadIdx.x;
  int isT = gid >= n;  // uniform per block (n % 256 == 0)
  const float* pts = isT ? target : base;
  int idx = isT ? gid - n : gid;
  float ex = __expf(log_scale[0]);
  float ey = __expf(log_scale[1]);
  float s2 = __expf(log_sigmas[2]);
  float r2 = __fsqrt_rn(L2E / (2.f * s2 * s2));  // coord pre-scale, band 2
  float2 p = ((const float2*)pts)[idx];
  float xr = p.x * ex, yr = p.y * ey;  // MLP input space (no r2!)
  float logit = b2[0];
#pragma unroll
  for (int k = 0; k < 32; ++k) {
    float h = fmaf(xr, w1[k], fmaf(yr, w1[32 + k], b1[k]));
    h = fmaxf(h, 0.f);
    logit = fmaf(h, w2[k], logit);
  }
  float u = fmaxf(logit, 0.f) + log1pf(__expf(-fabsf(logit))) + 1e-6f;
  float X = xr * r2, Y = yr * r2;
  pxy[gid] = make_float2(X, Y);
  pu[gid] = u;
  double su = bred((double)u, sm);
  double qu = bred((double)u * (double)u, sm);
  double mx = bred((double)u * (double)X, sm);
  double my = bred((double)u * (double)Y, sm);
  double sx = bred((double)X, sm);
  double sy = bred((double)Y, sm);
  double sr = bred((double)X * (double)X + (double)Y * (double)Y, sm);
  if (threadIdx.x == 0) {
    double* s = slot + blockIdx.x * 8;
    s[0] = su;
    s[1] = qu;
    s[2] = mx;
    s[3] = my;
    s[4] = sx;
    s[5] = sy;
    s[6] = sr;
    s[7] = 0.0;
    if (blockIdx.x == 0) {
      *fctr = 0u;
      *qctr = 0u;
    }
  }
}

// Packed-FP32 inner loop (round-0 proven core): v2f ops, pair = two j points.
// Sum of squared distances is closed-form from prep sums (no sq acc here).
template <bool AB, bool FAST>
__device__ inline void tile_loop(const float* sx, const float* sy,
                                 const float* su, const float* snb,
                                 const v2f xi2[4], const v2f yi2[4],
                                 const v2f al2[4], float rr0, float rr1,
                                 v2f a0[4], v2f a1[4], v2f a2[4], float& sdo) {
  float sda = 0.f, sdb = 0.f;
  const v2f vz = {0.f, 0.f};
#pragma unroll 2
  for (int jj = 0; jj < JT / 2; ++jj) {
    v2f xj = *(const v2f*)&sx[2 * jj];
    v2f yj = *(const v2f*)&sy[2 * jj];
    v2f uj = *(const v2f*)&su[2 * jj];
    v2f nbj;
    if constexpr (AB) nbj = *(const v2f*)&snb[2 * jj];
#pragma unroll
    for (int i = 0; i < 4; ++i) {
      v2f dx = xi2[i] - xj;
      v2f dy = yi2[i] - yj;
      v2f pos = dx * dx + dy * dy;  // contracts to pk_fma; = scaled d2
      v2f k2 = {fexp2n(pos.x), fexp2n(pos.y)};
      v2f k0, k1;
      if constexpr (FAST) {
        v2f t = k2 * k2;
        k1 = t * t;  // k2^4  (sigma ratio 1:2)
        v2f t1 = k1 * k1;
        k0 = t1 * t1;  // k2^16 (sigma ratio 1:4)
      } else {
        v2f m1 = pos * rr1;
        v2f m0 = pos * rr0;
        k1 = {fexp2n(m1.x), fexp2n(m1.y)};
        k0 = {fexp2n(m0.x), fexp2n(m0.y)};
      }
      a0[i] += uj * k0;
      a1[i] += uj * k1;
      a2[i] += uj * k2;
      if constexpr (AB) {
        // uncentered scaled d2 = pos + al_i - bj; clamp vs cancellation
        v2f anb = al2[i] + nbj;
        v2f d2u = pos + anb;
        d2u = __builtin_elementwise_max(d2u, vz);
        sda += fsqrt(d2u.x);
        sdb += fsqrt(d2u.y);
      }
    }
  }
  sdo = sda + sdb;
}

__global__ __launch_bounds__(256) void pair_kernel(
    const float2* __restrict__ pxy, const float* __restrict__ pu,
    const double* __restrict__ slot, double* __restrict__ pblk,
    unsigned* __restrict__ fctr, unsigned* __restrict__ qctr,
    const float* __restrict__ log_sigmas, const float* __restrict__ g_w1,
    const float* __restrict__ g_b1, const float* __restrict__ g_w2,
    const float* __restrict__ g_b2, const float* __restrict__ bias,
    float* __restrict__ out, int n) {
  __shared__ __align__(16) float sx[JT];
  __shared__ __align__(16) float sy[JT];
  __shared__ __align__(16) float su[JT];
  __shared__ __align__(16) float snb[JT];
  __shared__ double sm[4];
  __shared__ double smean[16];
  __shared__ int sjob;
  __shared__ int lastf;

  // ---- block-start: global sums -> centering + type scales ----
  slot_reduce(slot, smean, 4);
  __syncthreads();
  double Sb = smean[0], St = smean[8];
  float cx = (float)(smean[2] / Sb - smean[10] / St);
  float cy = (float)(smean[3] / Sb - smean[11] / St);
  float cx2 = 2.f * cx, cy2 = 2.f * cy;
  float cc = cx * cx + cy * cy;
  double sc_aa = 1.0 / (Sb * Sb);
  double sc_bb = 1.0 / (St * St);
  double sc_ab = -2.0 / (Sb * St);

  float s0 = __expf(log_sigmas[0]);
  float s1 = __expf(log_sigmas[1]);
  float s2 = __expf(log_sigmas[2]);
  float rr0 = (s2 * s2) / (s0 * s0);
  float rr1 = (s2 * s2) / (s1 * s1);
  bool fast = (fabsf(rr0 - 16.f) <= 0.016f) && (fabsf(rr1 - 4.f) <= 0.004f);

  // ---- persistent job loop: per-thread f64 accumulation, no per-job bred --
  double cacc0 = 0.0, cacc1 = 0.0, cacc2 = 0.0, sdacc = 0.0;
  for (;;) {
    if (threadIdx.x == 0) sjob = (int)atomicAdd(qctr, 1u);
    __syncthreads();  // broadcasts sjob; also guards LDS restage vs prev reads
    int jb = sjob;
    if (jb >= NJOB) break;

    int m, it, jt = 0, j0;
    double wgt = 1.0;
    if (jb < NJOB_AB) {  // AB jobs first in queue; light tri jobs drain last
      m = 2;
      it = jb >> 7;           // 8 i-tiles
      j0 = (jb & 127) * JT;   // 128 j-chunks
    } else {
      int r = jb - NJOB_AB;
      m = (r < NJOB_TRI) ? 0 : 1;
      if (m == 1) r -= NJOB_TRI;
      int tile = r >> 4;
      int q = r & 15;
      int idx = tile, len = T8;
      it = 0;
      while (idx >= len) {
        idx -= len;
        --len;
        ++it;
      }
      jt = it + idx;
      j0 = jt * ITILE + q * JT;
      if (jt != it) wgt = 2.0;  // symmetric off-diag tiles
    }
    const float2* pxyI = pxy + ((m == 1) ? n : 0);
    const float* puI = pu + ((m == 1) ? n : 0);
    const float2* pxyJ = pxy + ((m == 0) ? 0 : n);
    const float* puJ = pu + ((m == 0) ? 0 : n);

    if (threadIdx.x < JT) {
      float2 v = pxyJ[j0 + threadIdx.x];
      sx[threadIdx.x] = v.x;
      sy[threadIdx.x] = v.y;
      su[threadIdx.x] = puJ[j0 + threadIdx.x];
      if (m == 2) snb[threadIdx.x] = -fmaf(cx2, v.x, cy2 * v.y);  // -beta_j
    }

    int i0 = it * ITILE + threadIdx.x;
    v2f xi2[4], yi2[4], al2[4];
    float u[4];
#pragma unroll
    for (int i = 0; i < 4; ++i) {
      float2 P = pxyI[i0 + i * 256];
      u[i] = puI[i0 + i * 256];
      float xv = P.x, yv = P.y, alv = 0.f;
      if (m == 2) {  // center i-side; alpha recovers uncentered distance
        xv -= cx;
        yv -= cy;
        alv = fmaf(cx2, xv, cy2 * yv) + cc;
      }
      xi2[i] = (v2f){xv, xv};
      yi2[i] = (v2f){yv, yv};
      al2[i] = (v2f){alv, alv};
    }
    __syncthreads();  // j-tile staged

    v2f a0[4] = {}, a1[4] = {}, a2[4] = {};
    float sd = 0.f;
    if (m == 2) {
      if (fast)
        tile_loop<true, true>(sx, sy, su, snb, xi2, yi2, al2, rr0, rr1, a0, a1,
                              a2, sd);
      else
        tile_loop<true, false>(sx, sy, su, snb, xi2, yi2, al2, rr0, rr1, a0,
                               a1, a2, sd);
    } else {
      if (fast)
        tile_loop<false, true>(sx, sy, su, snb, xi2, yi2, al2, rr0, rr1, a0,
                               a1, a2, sd);
      else
        tile_loop<false, false>(sx, sy, su, snb, xi2, yi2, al2, rr0, rr1, a0,
                                a1, a2, sd);
    }

    double jc0 = 0.0, jc1 = 0.0, jc2 = 0.0;
#pragma unroll
    for (int i = 0; i < 4; ++i) {
      jc0 += (double)u[i] * (double)(a0[i].x + a0[i].y);
      jc1 += (double)u[i] * (double)(a1[i].x + a1[i].y);
      jc2 += (double)u[i] * (double)(a2[i].x + a2[i].y);
    }
    double jscale = ((m == 0) ? sc_aa : (m == 1) ? sc_bb : sc_ab) * wgt;
    cacc0 += jscale * jc0;
    cacc1 += jscale * jc1;
    cacc2 += jscale * jc2;
    if (m == 2) sdacc += (double)sd;
  }

  // ---- once per block: reduce and stash partials ----
  double r0 = bred(cacc0, sm);
  double r1 = bred(cacc1, sm);
  double r2d = bred(cacc2, sm);
  double rsd = bred(sdacc, sm);
  if (threadIdx.x == 0) {
    double* p = pblk + (size_t)blockIdx.x * 4;
    p[0] = r0;
    p[1] = r1;
    p[2] = r2d;
    p[3] = rsd;
  }

  // ---- last-block final reduction (ticket + device fence) ----
  if (threadIdx.x == 0) {
    __threadfence();
    unsigned old = atomicAdd(fctr, 1u);
    lastf = (old == GRID - 1) ? 1 : 0;
  }
  __syncthreads();
  if (!lastf) return;
  __threadfence();

  slot_reduce(slot, smean, 7);
  __syncthreads();
  int t = threadIdx.x;
  double v0 = 0.0, v1 = 0.0, v2 = 0.0, vs = 0.0;
#pragma unroll
  for (int q = 0; q < GRID / 256; ++q) {
    const double* p = pblk + (size_t)(t + 256 * q) * 4;
    v0 += p[0];
    v1 += p[1];
    v2 += p[2];
    vs += p[3];
  }
  v0 = bred(v0, sm);
  v1 = bred(v1, sm);
  v2 = bred(v2, sm);
  vs = bred(vs, sm);

  if (threadIdx.x == 0) {
    double Sb2 = smean[0], Qb = smean[1], St2 = smean[8], Qt = smean[9];
    double SXb = smean[4], SYb = smean[5], SRb = smean[6];
    double SXt = smean[12], SYt = smean[13], SRt = smean[14];
    double pband[3] = {v0, v1, v2};  // type scales already applied
    double NN = (double)n;
    // closed-form sum of squared distances (scaled space):
    // sum_ij |pi-pj|^2 = n*SRb + n*SRt - 2*(SXb*SXt + SYb*SYt)
    double sq_sc = NN * (SRb + SRt) - 2.0 * (SXb * SXt + SYb * SYt);
    double s2d = (double)s2;
    double r2sq = (double)L2E / (2.0 * s2d * s2d);
    double sd_real = vs / sqrt(r2sq);
    double sq_real = sq_sc / r2sq;
    double NM = NN * NN;
    double mean_d = sd_real / NM;
    double var_d = (sq_real - sd_real * sd_real / NM) / (NM - 1.0);
    double wv = (Qb / (Sb2 * Sb2) - 1.0 / NN) / (NN - 1.0) +
                (Qt / (St2 * St2) - 1.0 / NN) / (NN - 1.0);
    float st[4] = {(float)mean_d, (float)var_d, 0.f, (float)wv};
    float gl[3] = {g_b2[0], g_b2[1], g_b2[2]};
    for (int k = 0; k < 32; ++k) {
      float h = g_b1[k];
      for (int c = 0; c < 4; ++c) h = fmaf(st[c], g_w1[c * 32 + k], h);
      h = fmaxf(h, 0.f);
      for (int s = 0; s < 3; ++s) gl[s] = fmaf(h, g_w2[k * 3 + s], gl[s]);
    }
    float gw[3];
    float gsum = 0.f;
    for (int s = 0; s < 3; ++s) {
      gw[s] = fmaxf(gl[s], 0.f) + log1pf(__expf(-fabsf(gl[s])));
      gsum += gw[s];
    }
    double r = 0.0;
    for (int s = 0; s < 3; ++s) r += (double)(gw[s] / gsum) * pband[s];
    out[0] = (float)(r + (double)bias[0]);
  }
}

extern "C" void kernel_launch(void* const* d_in, const int* in_sizes, int n_in,
                              void* d_out, int out_size, void* d_ws,
                              size_t ws_size, hipStream_t stream) {
  const float* base = (const float*)d_in[0];
  const float* target = (const float*)d_in[1];
  const float* log_sigmas = (const float*)d_in[2];
  const float* log_scale = (const float*)d_in[3];
  const float* wn_w1 = (const float*)d_in[4];
  const float* wn_b1 = (const float*)d_in[5];
  const float* wn_w2 = (const float*)d_in[6];
  const float* wn_b2 = (const float*)d_in[7];
  const float* g_w1 = (const float*)d_in[8];
  const float* g_b1 = (const float*)d_in[9];
  const float* g_w2 = (const float*)d_in[10];
  const float* g_b2 = (const float*)d_in[11];
  const float* bias = (const float*)d_in[12];
  int n = in_sizes[0] / 2;  // 8192

  double* dbase = (double*)d_ws;
  double* slot = dbase;                 // 64*8 = 512
  double* pblk = dbase + 512;           // GRID*4 = 8192
  double* dend = pblk + GRID * 4;
  float2* pxy = (float2*)dend;          // 2n
  float* pu = (float*)(pxy + 2 * n);    // 2n
  unsigned* fctr = (unsigned*)(pu + 2 * n);
  unsigned* qctr = fctr + 1;

  prep_kernel<<<(2 * n) / 256, 256, 0, stream>>>(
      base, target, log_sigmas, log_scale, wn_w1, wn_b1, wn_w2, wn_b2, pxy, pu,
      slot, fctr, qctr, n);
  pair_kernel<<<GRID, 256, 0, stream>>>(pxy, pu, slot, pblk, fctr, qctr,
                                        log_sigmas, g_w1, g_b1, g_w2, g_b2,
                                        bias, (float*)d_out, n);
}

// Round 6
// 146.018 us; speedup vs baseline: 1.2396x; 1.2396x over previous
//
#include <hip/hip_runtime.h>
#include <math.h>

#define JT 64                // j per block (LDS staged)
#define ITILE 1024           // i per block (4 per thread, 256 threads)
#define T8 8                 // 1024-tiles per dimension
#define NJOB_AB 1024         // 8 i-tiles * 128 j-chunks
#define NJOB_TRI 576         // 36 tri-tiles * 16 chunks
#define NBLK (NJOB_AB + 2 * NJOB_TRI)  // 2176
#define L2E 1.4426950408889634f

typedef float v2f __attribute__((ext_vector_type(2)));

// exp2(-x) in ONE instruction: neg folded into VOP3 input modifier.
__device__ inline float fexp2n(float x) {
  float r;
  asm("v_exp_f32 %0, -%1" : "=v"(r) : "v"(x));
  return r;
}
__device__ inline float fsqrt(float x) {
  float r;
  asm("v_sqrt_f32 %0, %1" : "=v"(r) : "v"(x));
  return r;
}

__device__ inline double wred_d(double v) {
#pragma unroll
  for (int o = 32; o > 0; o >>= 1) v += __shfl_down(v, o, 64);
  return v;
}

__device__ inline double bred(double v, double* sm) {
  v = wred_d(v);
  __syncthreads();
  if ((threadIdx.x & 63) == 0) sm[threadIdx.x >> 6] = v;
  __syncthreads();
  return sm[0] + sm[1] + sm[2] + sm[3];
}

// wave 0: reduce 64 prep slots (stride 8) -> smean[c]=base, smean[8+c]=target
__device__ inline void slot_reduce(const double* slot, double* smean, int nc) {
  if (threadIdx.x < 64) {
    int l = threadIdx.x;
    const double* sl = slot + l * 8;
    for (int c = 0; c < nc; ++c) {
      double v = sl[c];
      double vb = (l < 32) ? v : 0.0;
      double vt = (l < 32) ? 0.0 : v;
      vb = wred_d(vb);
      vt = wred_d(vt);
      if (l == 0) {
        smean[c] = vb;
        smean[8 + c] = vt;
      }
    }
  }
}

__global__ __launch_bounds__(256) void prep_kernel(
    const float* __restrict__ base, const float* __restrict__ target,
    const float* __restrict__ log_sigmas, const float* __restrict__ log_scale,
    const float* __restrict__ w1, const float* __restrict__ b1,
    const float* __restrict__ w2, const float* __restrict__ b2,
    float2* __restrict__ pxy, float* __restrict__ pu,
    double* __restrict__ slot, unsigned* __restrict__ fctr, int n) {
  __shared__ double sm[4];
  int gid = blockIdx.x * 256 + threadIdx.x;
  int isT = gid >= n;  // uniform per block (n % 256 == 0)
  const float* pts = isT ? target : base;
  int idx = isT ? gid - n : gid;
  float ex = __expf(log_scale[0]);
  float ey = __expf(log_scale[1]);
  float s2 = __expf(log_sigmas[2]);
  float r2 = __fsqrt_rn(L2E / (2.f * s2 * s2));  // coord pre-scale, band 2
  float2 p = ((const float2*)pts)[idx];
  float xr = p.x * ex, yr = p.y * ey;  // MLP input space (no r2!)
  float logit = b2[0];
#pragma unroll
  for (int k = 0; k < 32; ++k) {
    float h = fmaf(xr, w1[k], fmaf(yr, w1[32 + k], b1[k]));
    h = fmaxf(h, 0.f);
    logit = fmaf(h, w2[k], logit);
  }
  float u = fmaxf(logit, 0.f) + log1pf(__expf(-fabsf(logit))) + 1e-6f;
  float X = xr * r2, Y = yr * r2;
  pxy[gid] = make_float2(X, Y);
  pu[gid] = u;
  double su = bred((double)u, sm);
  double qu = bred((double)u * (double)u, sm);
  double mx = bred((double)u * (double)X, sm);
  double my = bred((double)u * (double)Y, sm);
  double sx = bred((double)X, sm);
  double sy = bred((double)Y, sm);
  double sr = bred((double)X * (double)X + (double)Y * (double)Y, sm);
  if (threadIdx.x == 0) {
    double* s = slot + blockIdx.x * 8;
    s[0] = su;
    s[1] = qu;
    s[2] = mx;
    s[3] = my;
    s[4] = sx;
    s[5] = sy;
    s[6] = sr;
    s[7] = 0.0;
    if (blockIdx.x == 0) *fctr = 0u;
  }
}

// Packed-FP32 inner loop, expanded-dot form:
// pos = (xin*xj + yin*yj + rj) + ric  with xin=-2xi, ric=|pi|^2, rj=|pj|^2.
// AB reuses the cross term: d2u = core + (ric+al)_i + nb_j (uncentered d2).
template <bool AB, bool FAST>
__device__ inline void tile_loop(const float* sx, const float* sy,
                                 const float* sr, const float* su,
                                 const float* snb, const v2f xin2[4],
                                 const v2f yin2[4], const v2f ric2[4],
                                 const v2f rca2[4], float rr0, float rr1,
                                 v2f a0[4], v2f a1[4], v2f a2[4], v2f& sdv) {
  const v2f vz = {0.f, 0.f};
#pragma unroll 2
  for (int jj = 0; jj < JT / 2; ++jj) {
    v2f xj = *(const v2f*)&sx[2 * jj];
    v2f yj = *(const v2f*)&sy[2 * jj];
    v2f rj = *(const v2f*)&sr[2 * jj];
    v2f uj = *(const v2f*)&su[2 * jj];
    v2f nbj;
    if constexpr (AB) nbj = *(const v2f*)&snb[2 * jj];
#pragma unroll
    for (int i = 0; i < 4; ++i) {
      v2f core = xin2[i] * xj + (yin2[i] * yj + rj);  // 2 pk_fma (contract)
      v2f pos = core + ric2[i];                       // centered scaled d2
      v2f k2 = {fexp2n(pos.x), fexp2n(pos.y)};
      v2f k0, k1;
      if constexpr (FAST) {
        v2f t = k2 * k2;
        k1 = t * t;  // k2^4  (sigma ratio 1:2)
        v2f t1 = k1 * k1;
        k0 = t1 * t1;  // k2^16 (sigma ratio 1:4)
      } else {
        v2f m1 = pos * rr1;
        v2f m0 = pos * rr0;
        k1 = {fexp2n(m1.x), fexp2n(m1.y)};
        k0 = {fexp2n(m0.x), fexp2n(m0.y)};
      }
      a0[i] += uj * k0;
      a1[i] += uj * k1;
      a2[i] += uj * k2;
      if constexpr (AB) {
        // uncentered scaled d2 = core + (ric+al)_i + nb_j; clamp vs cancel
        v2f d2u = core + (rca2[i] + nbj);
        d2u = __builtin_elementwise_max(d2u, vz);
        v2f s = {fsqrt(d2u.x), fsqrt(d2u.y)};
        sdv += s;
      }
    }
  }
}

__global__ __launch_bounds__(256) void pair_kernel(
    const float2* __restrict__ pxy, const float* __restrict__ pu,
    const double* __restrict__ slot, double* __restrict__ paa,
    double* __restrict__ pbb, double* __restrict__ pab,
    double* __restrict__ psd, unsigned* __restrict__ fctr,
    const float* __restrict__ log_sigmas, const float* __restrict__ g_w1,
    const float* __restrict__ g_b1, const float* __restrict__ g_w2,
    const float* __restrict__ g_b2, const float* __restrict__ bias,
    float* __restrict__ out, int n) {
  __shared__ __align__(16) float sx[JT];
  __shared__ __align__(16) float sy[JT];
  __shared__ __align__(16) float sr[JT];
  __shared__ __align__(16) float su[JT];
  __shared__ __align__(16) float snb[JT];
  __shared__ double sm[4];
  __shared__ double smq[16];  // 4 warps x {c0,c1,c2,sd}
  __shared__ double smean[16];
  __shared__ int lastf;

  int b = blockIdx.x;
  int m, it, jt = 0, j0, pidx;
  if (b < NJOB_AB) {  // AB first (heavier), light tri jobs drain last
    m = 2;
    pidx = b;
    it = b >> 7;          // 8 i-tiles
    j0 = (b & 127) * JT;  // 128 j-chunks
  } else {
    int r = b - NJOB_AB;
    m = (r < NJOB_TRI) ? 0 : 1;
    if (m == 1) r -= NJOB_TRI;
    pidx = r;
    int tile = r >> 4;
    int q = r & 15;
    int idx = tile, len = T8;
    it = 0;
    while (idx >= len) {
      idx -= len;
      --len;
      ++it;
    }
    jt = it + idx;
    j0 = jt * ITILE + q * JT;
  }
  const float2* pxyI = pxy + ((m == 1) ? n : 0);
  const float* puI = pu + ((m == 1) ? n : 0);
  const float2* pxyJ = pxy + ((m == 0) ? 0 : n);
  const float* puJ = pu + ((m == 0) ? 0 : n);

  float cx = 0.f, cy = 0.f, cx2 = 0.f, cy2 = 0.f, cc = 0.f;
  if (m == 2) {
    slot_reduce(slot, smean, 4);  // wave 0; consumed after the barrier below
  }

  float s0 = __expf(log_sigmas[0]);
  float s1 = __expf(log_sigmas[1]);
  float s2 = __expf(log_sigmas[2]);
  float rr0 = (s2 * s2) / (s0 * s0);
  float rr1 = (s2 * s2) / (s1 * s1);
  bool fast = (fabsf(rr0 - 16.f) <= 0.016f) && (fabsf(rr1 - 4.f) <= 0.004f);

  if (m == 2) {
    __syncthreads();
    cx = (float)(smean[2] / smean[0] - smean[10] / smean[8]);
    cy = (float)(smean[3] / smean[0] - smean[11] / smean[8]);
    cx2 = 2.f * cx;
    cy2 = 2.f * cy;
    cc = cx * cx + cy * cy;
  }

  if (threadIdx.x < JT) {
    float2 v = pxyJ[j0 + threadIdx.x];
    sx[threadIdx.x] = v.x;
    sy[threadIdx.x] = v.y;
    sr[threadIdx.x] = fmaf(v.x, v.x, v.y * v.y);  // |pj|^2 (raw coords)
    su[threadIdx.x] = puJ[j0 + threadIdx.x];
    if (m == 2) snb[threadIdx.x] = -fmaf(cx2, v.x, cy2 * v.y);  // -beta_j
  }
  __syncthreads();

  int i0 = it * ITILE + threadIdx.x;
  v2f xin2[4], yin2[4], ric2[4], rca2[4];
  float u[4];
#pragma unroll
  for (int i = 0; i < 4; ++i) {
    float2 P = pxyI[i0 + i * 256];
    u[i] = puI[i0 + i * 256];
    float xv = P.x, yv = P.y, alv = 0.f;
    if (m == 2) {  // center i-side; alpha recovers uncentered distance
      xv -= cx;
      yv -= cy;
      alv = fmaf(cx2, xv, cy2 * yv) + cc;
    }
    float ric = fmaf(xv, xv, yv * yv);
    xin2[i] = (v2f){-2.f * xv, -2.f * xv};
    yin2[i] = (v2f){-2.f * yv, -2.f * yv};
    ric2[i] = (v2f){ric, ric};
    rca2[i] = (v2f){ric + alv, ric + alv};
  }

  v2f a0[4] = {}, a1[4] = {}, a2[4] = {};
  v2f sdv = {0.f, 0.f};
  if (m == 2) {
    if (fast)
      tile_loop<true, true>(sx, sy, sr, su, snb, xin2, yin2, ric2, rca2, rr0,
                            rr1, a0, a1, a2, sdv);
    else
      tile_loop<true, false>(sx, sy, sr, su, snb, xin2, yin2, ric2, rca2, rr0,
                             rr1, a0, a1, a2, sdv);
  } else {
    if (fast)
      tile_loop<false, true>(sx, sy, sr, su, snb, xin2, yin2, ric2, rca2, rr0,
                             rr1, a0, a1, a2, sdv);
    else
      tile_loop<false, false>(sx, sy, sr, su, snb, xin2, yin2, ric2, rca2, rr0,
                              rr1, a0, a1, a2, sdv);
  }

  // ---- per-job tail: 4 interleaved wave reductions, ONE barrier ----
  double c0 = 0.0, c1 = 0.0, c2 = 0.0;
#pragma unroll
  for (int i = 0; i < 4; ++i) {
    c0 += (double)u[i] * (double)(a0[i].x + a0[i].y);
    c1 += (double)u[i] * (double)(a1[i].x + a1[i].y);
    c2 += (double)u[i] * (double)(a2[i].x + a2[i].y);
  }
  double sdd = (double)(sdv.x + sdv.y);
  c0 = wred_d(c0);
  c1 = wred_d(c1);
  c2 = wred_d(c2);
  sdd = wred_d(sdd);
  if ((threadIdx.x & 63) == 0) {
    double* q = &smq[(threadIdx.x >> 6) * 4];
    q[0] = c0;
    q[1] = c1;
    q[2] = c2;
    q[3] = sdd;
  }
  __syncthreads();
  if (threadIdx.x == 0) {
    double wgt = (m != 2 && jt != it) ? 2.0 : 1.0;  // symmetric off-diag
    double t0 = smq[0] + smq[4] + smq[8] + smq[12];
    double t1 = smq[1] + smq[5] + smq[9] + smq[13];
    double t2 = smq[2] + smq[6] + smq[10] + smq[14];
    double ts = smq[3] + smq[7] + smq[11] + smq[15];
    double* prow = (m == 0) ? paa : (m == 1) ? pbb : pab;
    int stride = (m == 2) ? NJOB_AB : NJOB_TRI;
    prow[0 * stride + pidx] = t0 * wgt;
    prow[1 * stride + pidx] = t1 * wgt;
    prow[2 * stride + pidx] = t2 * wgt;
    if (m == 2) psd[pidx] = ts;
  }

  // ---- last-block final reduction (ticket + device fence) ----
  if (threadIdx.x == 0) {
    __threadfence();
    unsigned old = atomicAdd(fctr, 1u);
    lastf = (old == NBLK - 1) ? 1 : 0;
  }
  __syncthreads();
  if (!lastf) return;
  __threadfence();

  slot_reduce(slot, smean, 7);
  __syncthreads();
  int t = threadIdx.x;
  double vaa[3], vbb[3], vab[3];
  for (int s = 0; s < 3; ++s) {
    const double* pa = paa + s * NJOB_TRI;
    const double* pb = pbb + s * NJOB_TRI;
    const double* pc = pab + s * NJOB_AB;
    double va = pa[t] + pa[t + 256] + ((t < 64) ? pa[t + 512] : 0.0);
    double vb = pb[t] + pb[t + 256] + ((t < 64) ? pb[t + 512] : 0.0);
    double vc = pc[t] + pc[t + 256] + pc[t + 512] + pc[t + 768];
    vaa[s] = bred(va, sm);
    vbb[s] = bred(vb, sm);
    vab[s] = bred(vc, sm);
  }
  double sdg = psd[t] + psd[t + 256] + psd[t + 512] + psd[t + 768];
  double sdt = bred(sdg, sm);

  if (threadIdx.x == 0) {
    double Sb = smean[0], Qb = smean[1], St = smean[8], Qt = smean[9];
    double SXb = smean[4], SYb = smean[5], SRb = smean[6];
    double SXt = smean[12], SYt = smean[13], SRt = smean[14];
    double pband[3];
    for (int s = 0; s < 3; ++s)
      pband[s] = vaa[s] / (Sb * Sb) + vbb[s] / (St * St) -
                 2.0 * vab[s] / (Sb * St);
    double NN = (double)n;
    // closed-form sum of squared distances (scaled space):
    // sum_ij |pi-pj|^2 = n*SRb + n*SRt - 2*(SXb*SXt + SYb*SYt)
    double sq_sc = NN * (SRb + SRt) - 2.0 * (SXb * SXt + SYb * SYt);
    double s2d = (double)s2;
    double r2sq = (double)L2E / (2.0 * s2d * s2d);
    double sd_real = sdt / sqrt(r2sq);
    double sq_real = sq_sc / r2sq;
    double NM = NN * NN;
    double mean_d = sd_real / NM;
    double var_d = (sq_real - sd_real * sd_real / NM) / (NM - 1.0);
    double wv = (Qb / (Sb * Sb) - 1.0 / NN) / (NN - 1.0) +
                (Qt / (St * St) - 1.0 / NN) / (NN - 1.0);
    float st[4] = {(float)mean_d, (float)var_d, 0.f, (float)wv};
    float gl[3] = {g_b2[0], g_b2[1], g_b2[2]};
    for (int k = 0; k < 32; ++k) {
      float h = g_b1[k];
      for (int c = 0; c < 4; ++c) h = fmaf(st[c], g_w1[c * 32 + k], h);
      h = fmaxf(h, 0.f);
      for (int s = 0; s < 3; ++s) gl[s] = fmaf(h, g_w2[k * 3 + s], gl[s]);
    }
    float gw[3];
    float gsum = 0.f;
    for (int s = 0; s < 3; ++s) {
      gw[s] = fmaxf(gl[s], 0.f) + log1pf(__expf(-fabsf(gl[s])));
      gsum += gw[s];
    }
    double r = 0.0;
    for (int s = 0; s < 3; ++s) r += (double)(gw[s] / gsum) * pband[s];
    out[0] = (float)(r + (double)bias[0]);
  }
}

extern "C" void kernel_launch(void* const* d_in, const int* in_sizes, int n_in,
                              void* d_out, int out_size, void* d_ws,
                              size_t ws_size, hipStream_t stream) {
  const float* base = (const float*)d_in[0];
  const float* target = (const float*)d_in[1];
  const float* log_sigmas = (const float*)d_in[2];
  const float* log_scale = (const float*)d_in[3];
  const float* wn_w1 = (const float*)d_in[4];
  const float* wn_b1 = (const float*)d_in[5];
  const float* wn_w2 = (const float*)d_in[6];
  const float* wn_b2 = (const float*)d_in[7];
  const float* g_w1 = (const float*)d_in[8];
  const float* g_b1 = (const float*)d_in[9];
  const float* g_w2 = (const float*)d_in[10];
  const float* g_b2 = (const float*)d_in[11];
  const float* bias = (const float*)d_in[12];
  int n = in_sizes[0] / 2;  // 8192

  double* dbase = (double*)d_ws;
  double* slot = dbase;                // 64*8 = 512
  double* paa = dbase + 512;           // 3*576
  double* pbb = paa + 3 * NJOB_TRI;    // 3*576
  double* pab = pbb + 3 * NJOB_TRI;    // 3*1024
  double* psd = pab + 3 * NJOB_AB;     // 1024
  double* dend = psd + NJOB_AB;
  float2* pxy = (float2*)dend;         // 2n
  float* pu = (float*)(pxy + 2 * n);   // 2n
  unsigned* fctr = (unsigned*)(pu + 2 * n);

  prep_kernel<<<(2 * n) / 256, 256, 0, stream>>>(
      base, target, log_sigmas, log_scale, wn_w1, wn_b1, wn_w2, wn_b2, pxy, pu,
      slot, fctr, n);
  pair_kernel<<<NBLK, 256, 0, stream>>>(pxy, pu, slot, paa, pbb, pab, psd,
                                        fctr, log_sigmas, g_w1, g_b1, g_w2,
                                        g_b2, bias, (float*)d_out, n);
}